// Round 8
// baseline (394.550 us; speedup 1.0000x reference)
//
#include <hip/hip_runtime.h>

typedef __bf16 bf16x8 __attribute__((ext_vector_type(8)));
typedef float f32x4 __attribute__((ext_vector_type(4)));
typedef short s16x8 __attribute__((ext_vector_type(8)));

#define DEV __device__ __forceinline__

DEV float b2f(unsigned short u) {
  unsigned int x = ((unsigned int)u) << 16;
  return __builtin_bit_cast(float, x);
}
DEV unsigned short f2b(float f) {
  unsigned int x = __builtin_bit_cast(unsigned int, f);
  x += 0x7fffu + ((x >> 16) & 1u);
  return (unsigned short)(x >> 16);
}
DEV f32x4 mfma16(bf16x8 a, bf16x8 b, f32x4 c) {
  return __builtin_amdgcn_mfma_f32_16x16x32_bf16(a, b, c, 0, 0, 0);
}
DEV void gl2lds16(const unsigned short* g, unsigned short* l) {
  __builtin_amdgcn_global_load_lds(
      (const __attribute__((address_space(1))) void*)g,
      (__attribute__((address_space(3))) void*)l, 16, 0, 0);
}

// ------- tiled transpose + f32->bf16 convert: in[K][N] f32 (+z) -> out[N][K] bf16 -------
__global__ __launch_bounds__(256)
void transpose_k(const float* __restrict__ in, unsigned short* __restrict__ out,
                 int K, int N, long zin, long zout) {
  __shared__ float tile[32][33];
  in  += (size_t)blockIdx.z * zin;
  out += (size_t)blockIdx.z * zout;
  int n0 = blockIdx.x * 32, k0 = blockIdx.y * 32;
  int tx = threadIdx.x, ty = threadIdx.y;
  #pragma unroll
  for (int i = ty; i < 32; i += 8)
    tile[i][tx] = in[(size_t)(k0 + i) * N + n0 + tx];
  __syncthreads();
  #pragma unroll
  for (int i = ty; i < 32; i += 8)
    out[(size_t)(n0 + i) * K + k0 + tx] = f2b(tile[tx][i]);
}

// ------- V transpose: qkv v-cols [token][d] -> vT[bh][d][2048] (bf16->bf16) -------
__global__ __launch_bounds__(256)
void vtrans_k(const unsigned short* __restrict__ qkv, unsigned short* __restrict__ vT) {
  __shared__ unsigned short tile[32][33];
  int bh = blockIdx.z, b = bh >> 4, h = bh & 15;
  int t0 = blockIdx.x * 32, d0 = blockIdx.y * 32;
  const unsigned short* in = qkv + (size_t)b * 2048 * 3072 + 2048 + h * 64;
  unsigned short* out = vT + (size_t)bh * 64 * 2048;
  int tx = threadIdx.x, ty = threadIdx.y;
  #pragma unroll
  for (int i = ty; i < 32; i += 8)
    tile[i][tx] = in[(size_t)(t0 + i) * 3072 + d0 + tx];
  __syncthreads();
  #pragma unroll
  for (int i = ty; i < 32; i += 8)
    out[(size_t)(d0 + i) * 2048 + t0 + tx] = tile[tx][i];
}

// ---------------- LayerNorm over rows of 1024: f32 in -> bf16 out ----------------
__global__ __launch_bounds__(256)
void ln_kernel(const float* __restrict__ x, const float* __restrict__ g,
               const float* __restrict__ b, unsigned short* __restrict__ o) {
  __shared__ float rs[4];
  __shared__ float rq[4];
  int row = blockIdx.x, tid = threadIdx.x;
  const float* xr = x + (size_t)row * 1024;
  float4 raw = ((const float4*)xr)[tid];
  float s = raw.x + raw.y + raw.z + raw.w;
  float q = raw.x*raw.x + raw.y*raw.y + raw.z*raw.z + raw.w*raw.w;
  #pragma unroll
  for (int off = 32; off > 0; off >>= 1) {
    s += __shfl_down(s, off);
    q += __shfl_down(q, off);
  }
  int wave = tid >> 6;
  if ((tid & 63) == 0) { rs[wave] = s; rq[wave] = q; }
  __syncthreads();
  float ts = rs[0] + rs[1] + rs[2] + rs[3];
  float tq = rq[0] + rq[1] + rq[2] + rq[3];
  float mean = ts * (1.0f/1024.0f);
  float var = tq * (1.0f/1024.0f) - mean*mean;
  float rstd = rsqrtf(var + 1e-5f);
  float4 gr = ((const float4*)g)[tid];
  float4 br = ((const float4*)b)[tid];
  float o0 = (raw.x-mean)*rstd*gr.x + br.x;
  float o1 = (raw.y-mean)*rstd*gr.y + br.y;
  float o2 = (raw.z-mean)*rstd*gr.z + br.z;
  float o3 = (raw.w-mean)*rstd*gr.w + br.w;
  uint2 ov;
  ov.x = (unsigned int)f2b(o0) | ((unsigned int)f2b(o1) << 16);
  ov.y = (unsigned int)f2b(o2) | ((unsigned int)f2b(o3) << 16);
  ((uint2*)(o + (size_t)row * 1024))[tid] = ov;
}

// ------- GEMM 128x128: C[M][N] = A * Bt^T (+f32 bias/resid, relu), dbuf LDS -------
template<bool RELU, bool BIAS, bool RESID, bool OUTF32>
__global__ __launch_bounds__(256)
void gemm_bt(const unsigned short* __restrict__ A, const unsigned short* __restrict__ Bt,
             const float* __restrict__ bias, const float* __restrict__ resid,
             void* __restrict__ Cv, int M, int N, int K) {
  __shared__ unsigned short As[2][128*32];
  __shared__ unsigned short Bs[2][128*32];
  const int tid = threadIdx.x;
  const int lane = tid & 63;
  const int quad = lane >> 4, l16 = lane & 15;
  const int wave = tid >> 6;
  const int m0 = blockIdx.y * 128, n0 = blockIdx.x * 128;
  const int wm = (wave >> 1) * 64, wn = (wave & 1) * 64;

  f32x4 acc[4][4];
  #pragma unroll
  for (int i = 0; i < 4; ++i)
    #pragma unroll
    for (int j = 0; j < 4; ++j) acc[i][j] = (f32x4){0.f, 0.f, 0.f, 0.f};

  const int srow = tid >> 2;
  const int scol = (tid & 3) * 8;
  const unsigned short* Ab = A + (size_t)m0 * K;
  const unsigned short* Bb = Bt + (size_t)n0 * K;

  auto stage = [&](int buf, int k0) {
    gl2lds16(Ab + (size_t)srow * K + k0 + scol,        &As[buf][tid * 8]);
    gl2lds16(Ab + (size_t)(srow + 64) * K + k0 + scol, &As[buf][2048 + tid * 8]);
    gl2lds16(Bb + (size_t)srow * K + k0 + scol,        &Bs[buf][tid * 8]);
    gl2lds16(Bb + (size_t)(srow + 64) * K + k0 + scol, &Bs[buf][2048 + tid * 8]);
  };

  const int niter = K >> 5;
  stage(0, 0);
  __syncthreads();

  for (int it = 0; it < niter; ++it) {
    const int buf = it & 1;
    if (it + 1 < niter) stage(buf ^ 1, (it + 1) * 32);
    bf16x8 af[4], bfr[4];
    #pragma unroll
    for (int i = 0; i < 4; ++i)
      af[i] = __builtin_bit_cast(bf16x8, *(const s16x8*)&As[buf][(wm + i*16 + l16)*32 + quad*8]);
    #pragma unroll
    for (int j = 0; j < 4; ++j)
      bfr[j] = __builtin_bit_cast(bf16x8, *(const s16x8*)&Bs[buf][(wn + j*16 + l16)*32 + quad*8]);
    #pragma unroll
    for (int i = 0; i < 4; ++i)
      #pragma unroll
      for (int j = 0; j < 4; ++j)
        acc[i][j] = mfma16(af[i], bfr[j], acc[i][j]);
    __syncthreads();
  }

  #pragma unroll
  for (int i = 0; i < 4; ++i) {
    const int row = m0 + wm + i*16 + quad*4;
    #pragma unroll
    for (int j = 0; j < 4; ++j) {
      const int col = n0 + wn + j*16 + l16;
      float bv = 0.f;
      if (BIAS) bv = bias[col];
      #pragma unroll
      for (int r = 0; r < 4; ++r) {
        float v = acc[i][j][r] + bv;
        if (RESID) v += resid[(size_t)(row + r) * N + col];
        if (RELU) v = fmaxf(v, 0.f);
        if (OUTF32) ((float*)Cv)[(size_t)(row + r) * N + col] = v;
        else ((unsigned short*)Cv)[(size_t)(row + r) * N + col] = f2b(v);
      }
    }
  }
}

// ------- pipelined GEMM 128x128 for N=1024 outputs: C(f32) = A*Bt^T + bias + resid ----
// Triple-buffered gl2lds, prefetch depth 2, raw s_barrier + fine vmcnt (never drains
// the pipe). grid 256 = 1 block/CU. XCD swizzle: 4 m-tiles x 8 n-tiles per XCD.
__global__ __launch_bounds__(256)
void gemm_pipe(const unsigned short* __restrict__ A, const unsigned short* __restrict__ Bt,
               const float* __restrict__ bias, const float* __restrict__ resid,
               float* __restrict__ C, int M, int N, int K) {
  __shared__ unsigned short As[3][128*32];
  __shared__ unsigned short Bs[3][128*32];
  const int tid = threadIdx.x;
  const int lane = tid & 63;
  const int quad = lane >> 4, l16 = lane & 15;
  const int wave = tid >> 6;
  const int id = blockIdx.x;
  const int xcd = id & 7, i2 = id >> 3;        // i2: 0..31
  const int mt = (xcd << 2) | (i2 & 3);        // 0..31
  const int nt = i2 >> 2;                      // 0..7
  const int m0 = mt * 128, n0 = nt * 128;
  const int wm = (wave >> 1) * 64, wn = (wave & 1) * 64;

  f32x4 acc[4][4];
  #pragma unroll
  for (int i = 0; i < 4; ++i)
    #pragma unroll
    for (int j = 0; j < 4; ++j) acc[i][j] = (f32x4){0.f, 0.f, 0.f, 0.f};

  const int srow = tid >> 2;
  const int scol = (tid & 3) * 8;
  const unsigned short* Ab = A + (size_t)m0 * K;
  const unsigned short* Bb = Bt + (size_t)n0 * K;

  auto stage = [&](int buf, int k0) {
    gl2lds16(Ab + (size_t)srow * K + k0 + scol,        &As[buf][tid * 8]);
    gl2lds16(Ab + (size_t)(srow + 64) * K + k0 + scol, &As[buf][2048 + tid * 8]);
    gl2lds16(Bb + (size_t)srow * K + k0 + scol,        &Bs[buf][tid * 8]);
    gl2lds16(Bb + (size_t)(srow + 64) * K + k0 + scol, &Bs[buf][2048 + tid * 8]);
  };

  const int niter = K >> 5;        // >= 3 for all uses (min K = 1024)
  stage(0, 0);
  stage(1, 32);

  int buf = 0;
  for (int it = 0; it < niter; ++it) {
    // prefetch 2 ahead into the buffer last read at iteration it-1 (barrier-protected)
    if (it + 2 < niter) {
      const int nbuf = (buf == 0) ? 2 : buf - 1;
      stage(nbuf, (it + 2) * 32);
      // 12 in flight; wait until tile `it`'s 4 loads done, then sync waves
      __asm__ volatile("s_waitcnt vmcnt(8)\ns_barrier" ::: "memory");
    } else if (it + 1 < niter) {
      __asm__ volatile("s_waitcnt vmcnt(4)\ns_barrier" ::: "memory");
    } else {
      __asm__ volatile("s_waitcnt vmcnt(0)\ns_barrier" ::: "memory");
    }

    bf16x8 af[4], bfr[4];
    #pragma unroll
    for (int i = 0; i < 4; ++i)
      af[i] = __builtin_bit_cast(bf16x8, *(const s16x8*)&As[buf][(wm + i*16 + l16)*32 + quad*8]);
    #pragma unroll
    for (int j = 0; j < 4; ++j)
      bfr[j] = __builtin_bit_cast(bf16x8, *(const s16x8*)&Bs[buf][(wn + j*16 + l16)*32 + quad*8]);
    #pragma unroll
    for (int i = 0; i < 4; ++i)
      #pragma unroll
      for (int j = 0; j < 4; ++j)
        acc[i][j] = mfma16(af[i], bfr[j], acc[i][j]);

    // end-of-iter barrier: all waves done READING buf before it is restaged at it+1
    __asm__ volatile("s_barrier" ::: "memory");
    buf = (buf == 2) ? 0 : buf + 1;
  }

  #pragma unroll
  for (int i = 0; i < 4; ++i) {
    const int row = m0 + wm + i*16 + quad*4;
    #pragma unroll
    for (int j = 0; j < 4; ++j) {
      const int col = n0 + wn + j*16 + l16;
      const float bv = bias[col];
      #pragma unroll
      for (int r = 0; r < 4; ++r)
        C[(size_t)(row + r) * N + col] = acc[i][j][r] + bv + resid[(size_t)(row + r) * N + col];
    }
  }
}

// ---------------- causal flash attention, paired q-tiles + gl2lds double-buffer ------
__global__ __launch_bounds__(256)
void attn_kernel(const unsigned short* __restrict__ qkv,
                 const unsigned short* __restrict__ vT,
                 unsigned short* __restrict__ outc) {
  __shared__ unsigned short Ks[2][64*64];   // [kv][d], chunk-XOR swizzled
  __shared__ unsigned short Vs[2][64*64];   // [d][kv], chunk-XOR swizzled
  __shared__ unsigned short Ps[2][4*16*72]; // per-tile, per-wave P [16][72]
  const int tid = threadIdx.x, lane = tid & 63, wave = tid >> 6;
  const int quad = lane >> 4, l16 = lane & 15;
  const int bh = blockIdx.y, b = bh >> 4, h = bh & 15;
  const int jA = blockIdx.x, jB = 31 - jA;
  const size_t tokbase = (size_t)b * 2048 * 3072;
  const unsigned short* Q  = qkv + tokbase + h * 64;
  const unsigned short* Kg = qkv + tokbase + 1024 + h * 64;
  const unsigned short* Vg = vT + (size_t)bh * 64 * 2048;

  bf16x8 qf[2][2];
  #pragma unroll
  for (int t = 0; t < 2; ++t) {
    const int qrow = (t ? jB : jA) * 64 + wave * 16 + l16;
    #pragma unroll
    for (int s = 0; s < 2; ++s) {
      s16x8 raw = *(const s16x8*)(Q + (size_t)qrow * 3072 + s * 32 + quad * 8);
      unsigned short* rp = (unsigned short*)&raw;
      #pragma unroll
      for (int j = 0; j < 8; ++j) rp[j] = f2b(b2f(rp[j]) * 0.03125f);
      qf[t][s] = __builtin_bit_cast(bf16x8, raw);
    }
  }

  f32x4 accO[2][4];
  #pragma unroll
  for (int t = 0; t < 2; ++t)
    #pragma unroll
    for (int i = 0; i < 4; ++i) accO[t][i] = (f32x4){0.f, 0.f, 0.f, 0.f};
  float lrow[2][4] = {{0.f,0.f,0.f,0.f},{0.f,0.f,0.f,0.f}};

  const int r8 = lane >> 3;
  const int cs = (((lane & 7) ^ r8) * 8);

  auto stage = [&](int buf, int kv0) {
    #pragma unroll
    for (int i = 0; i < 2; ++i) {
      int row = wave * 16 + i * 8;
      gl2lds16(Kg + (size_t)(kv0 + row + r8) * 3072 + cs, &Ks[buf][row * 64 + lane * 8]);
      gl2lds16(Vg + (size_t)(row + r8) * 2048 + kv0 + cs, &Vs[buf][row * 64 + lane * 8]);
    }
  };

  const int ntile = jB + 1;
  stage(0, 0);
  __syncthreads();

  for (int it = 0; it < ntile; ++it) {
    const int buf = it & 1;
    if (it + 1 < ntile) stage(buf ^ 1, (it + 1) * 64);

    #pragma unroll
    for (int t = 0; t < 2; ++t) {
      const int jT = t ? jB : jA;
      if (it > jT) continue;
      f32x4 sv[4];
      #pragma unroll
      for (int ni = 0; ni < 4; ++ni) {
        sv[ni] = (f32x4){0.f, 0.f, 0.f, 0.f};
        #pragma unroll
        for (int s = 0; s < 2; ++s) {
          bf16x8 kf = __builtin_bit_cast(bf16x8,
            *(const s16x8*)&Ks[buf][(ni*16 + l16)*64 + (((s*4 + quad) ^ (l16 & 7)) * 8)]);
          sv[ni] = mfma16(qf[t][s], kf, sv[ni]);
        }
      }
      if (it == jT) {
        const int rowg = jT*64 + wave*16 + quad*4;
        const int kv0 = it * 64;
        #pragma unroll
        for (int ni = 0; ni < 4; ++ni) {
          const int colg = kv0 + ni*16 + l16;
          #pragma unroll
          for (int r = 0; r < 4; ++r)
            if (colg > rowg + r) sv[ni][r] = -__builtin_inff();
        }
      }
      float rsum[4] = {0.f, 0.f, 0.f, 0.f};
      unsigned short pb[4][4];
      #pragma unroll
      for (int ni = 0; ni < 4; ++ni)
        #pragma unroll
        for (int r = 0; r < 4; ++r) {
          float p = __expf(sv[ni][r]);
          rsum[r] += p;
          pb[ni][r] = f2b(p);
        }
      #pragma unroll
      for (int r = 0; r < 4; ++r) {
        float s2 = rsum[r];
        s2 += __shfl_xor(s2, 1);
        s2 += __shfl_xor(s2, 2);
        s2 += __shfl_xor(s2, 4);
        s2 += __shfl_xor(s2, 8);
        lrow[t][r] += s2;
      }
      #pragma unroll
      for (int ni = 0; ni < 4; ++ni)
        #pragma unroll
        for (int r = 0; r < 4; ++r)
          Ps[t][wave*1152 + (quad*4 + r)*72 + ni*16 + l16] = pb[ni][r];
      __asm__ volatile("s_waitcnt lgkmcnt(0)" ::: "memory");
      #pragma unroll
      for (int s = 0; s < 2; ++s) {
        bf16x8 pf = __builtin_bit_cast(bf16x8,
          *(const s16x8*)&Ps[t][wave*1152 + l16*72 + s*32 + quad*8]);
        #pragma unroll
        for (int ni = 0; ni < 4; ++ni) {
          bf16x8 vf = __builtin_bit_cast(bf16x8,
            *(const s16x8*)&Vs[buf][(ni*16 + l16)*64 + (((s*4 + quad) ^ (l16 & 7)) * 8)]);
          accO[t][ni] = mfma16(pf, vf, accO[t][ni]);
        }
      }
    }
    __syncthreads();
  }

  #pragma unroll
  for (int t = 0; t < 2; ++t) {
    const int rowg = (t ? jB : jA)*64 + wave*16 + quad*4;
    #pragma unroll
    for (int ni = 0; ni < 4; ++ni)
      #pragma unroll
      for (int r = 0; r < 4; ++r) {
        float o = accO[t][ni][r] / lrow[t][r];
        outc[(size_t)(b*2048 + rowg + r) * 1024 + h*64 + ni*16 + l16] = f2b(o);
      }
  }
}

extern "C" void kernel_launch(void* const* d_in, const int* in_sizes, int n_in,
                              void* d_out, int out_size, void* d_ws, size_t ws_size,
                              hipStream_t stream) {
  (void)in_sizes; (void)n_in; (void)out_size; (void)ws_size;
  const float* x   = (const float*)d_in[0];
  const float* wq  = (const float*)d_in[1];
  const float* wk  = (const float*)d_in[2];
  const float* wv  = (const float*)d_in[3];
  const float* wo  = (const float*)d_in[4];
  const float* bo  = (const float*)d_in[5];
  const float* g1  = (const float*)d_in[6];
  const float* b1  = (const float*)d_in[7];
  const float* g2  = (const float*)d_in[8];
  const float* b2  = (const float*)d_in[9];
  const float* w1  = (const float*)d_in[10];
  const float* bf1 = (const float*)d_in[11];
  const float* w2  = (const float*)d_in[12];
  const float* bf2 = (const float*)d_in[13];
  float* out = (float*)d_out;

  unsigned short* ws    = (unsigned short*)d_ws;
  unsigned short* wqkvt = ws;                        // bf16 [3072][1024]
  unsigned short* wot   = wqkvt + 3*1024*1024;       // bf16 [1024][1024]
  unsigned short* w1t   = wot   + 1024*1024;         // bf16 [4096][1024]
  unsigned short* w2t   = w1t   + 4096*1024;         // bf16 [1024][4096]
  unsigned short* hbuf  = w2t   + 4096*1024;         // bf16 [4096][1024] (LN1/LN2 out)
  unsigned short* qkvb  = hbuf  + 4096*1024;         // bf16 [4096][3072]
  unsigned short* attnb = qkvb  + (size_t)4096*3072; // bf16 [4096][1024]
  float*          x2b   = (float*)(attnb + 4096*1024); // f32 [4096][1024]
  unsigned short* vTb   = (unsigned short*)x2b;      // bf16 [32][64][2048] — dead before x2b written
  unsigned short* midb  = qkvb;                      // bf16 [4096][4096] overlaps qkvb+attnb (dead)

  dim3 tb(32, 8);
  transpose_k<<<dim3(2,32,16), tb, 0, stream>>>(wq, wqkvt,             1024, 64, 65536, 65536);
  transpose_k<<<dim3(2,32,16), tb, 0, stream>>>(wk, wqkvt + 1024*1024, 1024, 64, 65536, 65536);
  transpose_k<<<dim3(2,32,16), tb, 0, stream>>>(wv, wqkvt + 2048*1024, 1024, 64, 65536, 65536);
  transpose_k<<<dim3(32,32,1),  tb, 0, stream>>>(wo, wot, 1024, 1024, 0, 0);
  transpose_k<<<dim3(128,32,1), tb, 0, stream>>>(w1, w1t, 1024, 4096, 0, 0);
  transpose_k<<<dim3(32,128,1), tb, 0, stream>>>(w2, w2t, 4096, 1024, 0, 0);

  ln_kernel<<<4096, 256, 0, stream>>>(x, g1, b1, hbuf);
  gemm_bt<false,false,false,false><<<dim3(24,32), 256, 0, stream>>>(hbuf, wqkvt, nullptr, nullptr, qkvb, 4096, 3072, 1024);
  vtrans_k<<<dim3(64,2,32), tb, 0, stream>>>(qkvb, vTb);
  attn_kernel<<<dim3(16,32), 256, 0, stream>>>(qkvb, vTb, attnb);
  gemm_pipe<<<256, 256, 0, stream>>>(attnb, wot, bo, x, x2b, 4096, 1024, 1024);
  ln_kernel<<<4096, 256, 0, stream>>>(x2b, g2, b2, hbuf);
  gemm_bt<true,true,false,false><<<dim3(32,32), 256, 0, stream>>>(hbuf, w1t, bf1, nullptr, midb, 4096, 4096, 1024);
  gemm_pipe<<<256, 256, 0, stream>>>(midb, w2t, bf2, x2b, out, 4096, 1024, 4096);
}

// Round 9
// 366.538 us; speedup vs baseline: 1.0764x; 1.0764x over previous
//
#include <hip/hip_runtime.h>

typedef __bf16 bf16x8 __attribute__((ext_vector_type(8)));
typedef float f32x4 __attribute__((ext_vector_type(4)));
typedef short s16x8 __attribute__((ext_vector_type(8)));

#define DEV __device__ __forceinline__

DEV float b2f(unsigned short u) {
  unsigned int x = ((unsigned int)u) << 16;
  return __builtin_bit_cast(float, x);
}
DEV unsigned short f2b(float f) {
  unsigned int x = __builtin_bit_cast(unsigned int, f);
  x += 0x7fffu + ((x >> 16) & 1u);
  return (unsigned short)(x >> 16);
}
DEV f32x4 mfma16(bf16x8 a, bf16x8 b, f32x4 c) {
  return __builtin_amdgcn_mfma_f32_16x16x32_bf16(a, b, c, 0, 0, 0);
}
DEV void gl2lds16(const unsigned short* g, unsigned short* l) {
  __builtin_amdgcn_global_load_lds(
      (const __attribute__((address_space(1))) void*)g,
      (__attribute__((address_space(3))) void*)l, 16, 0, 0);
}

// ------- tiled transpose + f32->bf16 convert: in[K][N] f32 (+z) -> out[N][K] bf16 -------
__global__ __launch_bounds__(256)
void transpose_k(const float* __restrict__ in, unsigned short* __restrict__ out,
                 int K, int N, long zin, long zout) {
  __shared__ float tile[32][33];
  in  += (size_t)blockIdx.z * zin;
  out += (size_t)blockIdx.z * zout;
  int n0 = blockIdx.x * 32, k0 = blockIdx.y * 32;
  int tx = threadIdx.x, ty = threadIdx.y;
  #pragma unroll
  for (int i = ty; i < 32; i += 8)
    tile[i][tx] = in[(size_t)(k0 + i) * N + n0 + tx];
  __syncthreads();
  #pragma unroll
  for (int i = ty; i < 32; i += 8)
    out[(size_t)(n0 + i) * K + k0 + tx] = f2b(tile[tx][i]);
}

// ------- V transpose: qkv v-cols [token][d] -> vT[bh][d][2048] (bf16->bf16) -------
__global__ __launch_bounds__(256)
void vtrans_k(const unsigned short* __restrict__ qkv, unsigned short* __restrict__ vT) {
  __shared__ unsigned short tile[32][33];
  int bh = blockIdx.z, b = bh >> 4, h = bh & 15;
  int t0 = blockIdx.x * 32, d0 = blockIdx.y * 32;
  const unsigned short* in = qkv + (size_t)b * 2048 * 3072 + 2048 + h * 64;
  unsigned short* out = vT + (size_t)bh * 64 * 2048;
  int tx = threadIdx.x, ty = threadIdx.y;
  #pragma unroll
  for (int i = ty; i < 32; i += 8)
    tile[i][tx] = in[(size_t)(t0 + i) * 3072 + d0 + tx];
  __syncthreads();
  #pragma unroll
  for (int i = ty; i < 32; i += 8)
    out[(size_t)(d0 + i) * 2048 + t0 + tx] = tile[tx][i];
}

// ---------------- LayerNorm over rows of 1024: f32 in -> bf16 out ----------------
__global__ __launch_bounds__(256)
void ln_kernel(const float* __restrict__ x, const float* __restrict__ g,
               const float* __restrict__ b, unsigned short* __restrict__ o) {
  __shared__ float rs[4];
  __shared__ float rq[4];
  int row = blockIdx.x, tid = threadIdx.x;
  const float* xr = x + (size_t)row * 1024;
  float4 raw = ((const float4*)xr)[tid];
  float s = raw.x + raw.y + raw.z + raw.w;
  float q = raw.x*raw.x + raw.y*raw.y + raw.z*raw.z + raw.w*raw.w;
  #pragma unroll
  for (int off = 32; off > 0; off >>= 1) {
    s += __shfl_down(s, off);
    q += __shfl_down(q, off);
  }
  int wave = tid >> 6;
  if ((tid & 63) == 0) { rs[wave] = s; rq[wave] = q; }
  __syncthreads();
  float ts = rs[0] + rs[1] + rs[2] + rs[3];
  float tq = rq[0] + rq[1] + rq[2] + rq[3];
  float mean = ts * (1.0f/1024.0f);
  float var = tq * (1.0f/1024.0f) - mean*mean;
  float rstd = rsqrtf(var + 1e-5f);
  float4 gr = ((const float4*)g)[tid];
  float4 br = ((const float4*)b)[tid];
  float o0 = (raw.x-mean)*rstd*gr.x + br.x;
  float o1 = (raw.y-mean)*rstd*gr.y + br.y;
  float o2 = (raw.z-mean)*rstd*gr.z + br.z;
  float o3 = (raw.w-mean)*rstd*gr.w + br.w;
  uint2 ov;
  ov.x = (unsigned int)f2b(o0) | ((unsigned int)f2b(o1) << 16);
  ov.y = (unsigned int)f2b(o2) | ((unsigned int)f2b(o3) << 16);
  ((uint2*)(o + (size_t)row * 1024))[tid] = ov;
}

// ------- GEMM 128x128: C[M][N] = A * Bt^T (+f32 bias/resid, relu), dbuf LDS -------
template<bool RELU, bool BIAS, bool RESID, bool OUTF32>
__global__ __launch_bounds__(256)
void gemm_bt(const unsigned short* __restrict__ A, const unsigned short* __restrict__ Bt,
             const float* __restrict__ bias, const float* __restrict__ resid,
             void* __restrict__ Cv, int M, int N, int K) {
  __shared__ unsigned short As[2][128*32];
  __shared__ unsigned short Bs[2][128*32];
  const int tid = threadIdx.x;
  const int lane = tid & 63;
  const int quad = lane >> 4, l16 = lane & 15;
  const int wave = tid >> 6;
  const int m0 = blockIdx.y * 128, n0 = blockIdx.x * 128;
  const int wm = (wave >> 1) * 64, wn = (wave & 1) * 64;

  f32x4 acc[4][4];
  #pragma unroll
  for (int i = 0; i < 4; ++i)
    #pragma unroll
    for (int j = 0; j < 4; ++j) acc[i][j] = (f32x4){0.f, 0.f, 0.f, 0.f};

  const int srow = tid >> 2;
  const int scol = (tid & 3) * 8;
  const unsigned short* Ab = A + (size_t)m0 * K;
  const unsigned short* Bb = Bt + (size_t)n0 * K;

  auto stage = [&](int buf, int k0) {
    gl2lds16(Ab + (size_t)srow * K + k0 + scol,        &As[buf][tid * 8]);
    gl2lds16(Ab + (size_t)(srow + 64) * K + k0 + scol, &As[buf][2048 + tid * 8]);
    gl2lds16(Bb + (size_t)srow * K + k0 + scol,        &Bs[buf][tid * 8]);
    gl2lds16(Bb + (size_t)(srow + 64) * K + k0 + scol, &Bs[buf][2048 + tid * 8]);
  };

  const int niter = K >> 5;
  stage(0, 0);
  __syncthreads();

  for (int it = 0; it < niter; ++it) {
    const int buf = it & 1;
    if (it + 1 < niter) stage(buf ^ 1, (it + 1) * 32);
    bf16x8 af[4], bfr[4];
    #pragma unroll
    for (int i = 0; i < 4; ++i)
      af[i] = __builtin_bit_cast(bf16x8, *(const s16x8*)&As[buf][(wm + i*16 + l16)*32 + quad*8]);
    #pragma unroll
    for (int j = 0; j < 4; ++j)
      bfr[j] = __builtin_bit_cast(bf16x8, *(const s16x8*)&Bs[buf][(wn + j*16 + l16)*32 + quad*8]);
    #pragma unroll
    for (int i = 0; i < 4; ++i)
      #pragma unroll
      for (int j = 0; j < 4; ++j)
        acc[i][j] = mfma16(af[i], bfr[j], acc[i][j]);
    __syncthreads();
  }

  #pragma unroll
  for (int i = 0; i < 4; ++i) {
    const int row = m0 + wm + i*16 + quad*4;
    #pragma unroll
    for (int j = 0; j < 4; ++j) {
      const int col = n0 + wn + j*16 + l16;
      float bv = 0.f;
      if (BIAS) bv = bias[col];
      #pragma unroll
      for (int r = 0; r < 4; ++r) {
        float v = acc[i][j][r] + bv;
        if (RESID) v += resid[(size_t)(row + r) * N + col];
        if (RELU) v = fmaxf(v, 0.f);
        if (OUTF32) ((float*)Cv)[(size_t)(row + r) * N + col] = v;
        else ((unsigned short*)Cv)[(size_t)(row + r) * N + col] = f2b(v);
      }
    }
  }
}

// ------- GEMM 64x128, BK=64, chunk-XOR swizzled LDS, dbuf — for N=1024 outputs -------
// C(f32) = A*Bt^T + bias + resid. Latency-bound regime: halving iteration count
// (BK 32->64) halves exposed-latency time. grid 512 = 2 blocks/CU, LDS 48 KB.
// XCD swizzle: id&7 = xcd, each xcd owns an 8-m-tile stripe.
__global__ __launch_bounds__(256)
void gemm_n1024(const unsigned short* __restrict__ A, const unsigned short* __restrict__ Bt,
                const float* __restrict__ bias, const float* __restrict__ resid,
                float* __restrict__ C, int M, int N, int K) {
  __shared__ unsigned short As[2][64*64];    // [m][k], chunk-XOR swizzled rows
  __shared__ unsigned short Bs[2][128*64];
  const int tid = threadIdx.x;
  const int lane = tid & 63;
  const int quad = lane >> 4, l16 = lane & 15;
  const int wave = tid >> 6;
  const int id = blockIdx.x;
  const int xcd = id & 7, i2 = id >> 3;
  const int mt = (xcd << 3) | (i2 >> 3);   // 0..63
  const int nt = i2 & 7;                   // 0..7
  const int m0 = mt * 64, n0 = nt * 128;
  const int wm = (wave >> 1) * 32, wn = (wave & 1) * 64;

  f32x4 acc[2][4];
  #pragma unroll
  for (int i = 0; i < 2; ++i)
    #pragma unroll
    for (int j = 0; j < 4; ++j) acc[i][j] = (f32x4){0.f, 0.f, 0.f, 0.f};

  // staging map: per gl2lds covering 32 rows, lane t: row = rb + (t>>3),
  // LDS = base + t*8 (contiguous), global col chunk = (t&7) ^ ((t>>3)&7)
  const int srow = tid >> 3;                    // 0..31
  const int scc  = ((tid & 7) ^ (srow & 7)) * 8;
  const unsigned short* Ab = A + (size_t)m0 * K;
  const unsigned short* Bb = Bt + (size_t)n0 * K;

  auto stage = [&](int buf, int k0) {
    gl2lds16(Ab + (size_t)srow * K + k0 + scc,         &As[buf][tid * 8]);
    gl2lds16(Ab + (size_t)(srow + 32) * K + k0 + scc,  &As[buf][2048 + tid * 8]);
    gl2lds16(Bb + (size_t)srow * K + k0 + scc,         &Bs[buf][tid * 8]);
    gl2lds16(Bb + (size_t)(srow + 32) * K + k0 + scc,  &Bs[buf][2048 + tid * 8]);
    gl2lds16(Bb + (size_t)(srow + 64) * K + k0 + scc,  &Bs[buf][4096 + tid * 8]);
    gl2lds16(Bb + (size_t)(srow + 96) * K + k0 + scc,  &Bs[buf][6144 + tid * 8]);
  };

  const int niter = K >> 6;
  stage(0, 0);
  __syncthreads();

  for (int it = 0; it < niter; ++it) {
    const int buf = it & 1;
    if (it + 1 < niter) stage(buf ^ 1, (it + 1) * 64);
    #pragma unroll
    for (int s = 0; s < 2; ++s) {
      bf16x8 af[2], bfr[4];
      #pragma unroll
      for (int i = 0; i < 2; ++i) {
        const int R = wm + i*16 + l16;
        af[i] = __builtin_bit_cast(bf16x8,
          *(const s16x8*)&As[buf][R*64 + (((s*4 + quad) ^ (R & 7)) * 8)]);
      }
      #pragma unroll
      for (int j = 0; j < 4; ++j) {
        const int R = wn + j*16 + l16;
        bfr[j] = __builtin_bit_cast(bf16x8,
          *(const s16x8*)&Bs[buf][R*64 + (((s*4 + quad) ^ (R & 7)) * 8)]);
      }
      #pragma unroll
      for (int i = 0; i < 2; ++i)
        #pragma unroll
        for (int j = 0; j < 4; ++j)
          acc[i][j] = mfma16(af[i], bfr[j], acc[i][j]);
    }
    __syncthreads();
  }

  #pragma unroll
  for (int i = 0; i < 2; ++i) {
    const int row = m0 + wm + i*16 + quad*4;
    #pragma unroll
    for (int j = 0; j < 4; ++j) {
      const int col = n0 + wn + j*16 + l16;
      const float bv = bias[col];
      #pragma unroll
      for (int r = 0; r < 4; ++r)
        C[(size_t)(row + r) * N + col] = acc[i][j][r] + bv + resid[(size_t)(row + r) * N + col];
    }
  }
}

// ---------------- causal flash attention, paired q-tiles + gl2lds double-buffer ------
__global__ __launch_bounds__(256)
void attn_kernel(const unsigned short* __restrict__ qkv,
                 const unsigned short* __restrict__ vT,
                 unsigned short* __restrict__ outc) {
  __shared__ unsigned short Ks[2][64*64];   // [kv][d], chunk-XOR swizzled
  __shared__ unsigned short Vs[2][64*64];   // [d][kv], chunk-XOR swizzled
  __shared__ unsigned short Ps[2][4*16*72]; // per-tile, per-wave P [16][72]
  const int tid = threadIdx.x, lane = tid & 63, wave = tid >> 6;
  const int quad = lane >> 4, l16 = lane & 15;
  const int bh = blockIdx.y, b = bh >> 4, h = bh & 15;
  const int jA = blockIdx.x, jB = 31 - jA;
  const size_t tokbase = (size_t)b * 2048 * 3072;
  const unsigned short* Q  = qkv + tokbase + h * 64;
  const unsigned short* Kg = qkv + tokbase + 1024 + h * 64;
  const unsigned short* Vg = vT + (size_t)bh * 64 * 2048;

  bf16x8 qf[2][2];
  #pragma unroll
  for (int t = 0; t < 2; ++t) {
    const int qrow = (t ? jB : jA) * 64 + wave * 16 + l16;
    #pragma unroll
    for (int s = 0; s < 2; ++s) {
      s16x8 raw = *(const s16x8*)(Q + (size_t)qrow * 3072 + s * 32 + quad * 8);
      unsigned short* rp = (unsigned short*)&raw;
      #pragma unroll
      for (int j = 0; j < 8; ++j) rp[j] = f2b(b2f(rp[j]) * 0.03125f);
      qf[t][s] = __builtin_bit_cast(bf16x8, raw);
    }
  }

  f32x4 accO[2][4];
  #pragma unroll
  for (int t = 0; t < 2; ++t)
    #pragma unroll
    for (int i = 0; i < 4; ++i) accO[t][i] = (f32x4){0.f, 0.f, 0.f, 0.f};
  float lrow[2][4] = {{0.f,0.f,0.f,0.f},{0.f,0.f,0.f,0.f}};

  const int r8 = lane >> 3;
  const int cs = (((lane & 7) ^ r8) * 8);

  auto stage = [&](int buf, int kv0) {
    #pragma unroll
    for (int i = 0; i < 2; ++i) {
      int row = wave * 16 + i * 8;
      gl2lds16(Kg + (size_t)(kv0 + row + r8) * 3072 + cs, &Ks[buf][row * 64 + lane * 8]);
      gl2lds16(Vg + (size_t)(row + r8) * 2048 + kv0 + cs, &Vs[buf][row * 64 + lane * 8]);
    }
  };

  const int ntile = jB + 1;
  stage(0, 0);
  __syncthreads();

  for (int it = 0; it < ntile; ++it) {
    const int buf = it & 1;
    if (it + 1 < ntile) stage(buf ^ 1, (it + 1) * 64);

    #pragma unroll
    for (int t = 0; t < 2; ++t) {
      const int jT = t ? jB : jA;
      if (it > jT) continue;
      f32x4 sv[4];
      #pragma unroll
      for (int ni = 0; ni < 4; ++ni) {
        sv[ni] = (f32x4){0.f, 0.f, 0.f, 0.f};
        #pragma unroll
        for (int s = 0; s < 2; ++s) {
          bf16x8 kf = __builtin_bit_cast(bf16x8,
            *(const s16x8*)&Ks[buf][(ni*16 + l16)*64 + (((s*4 + quad) ^ (l16 & 7)) * 8)]);
          sv[ni] = mfma16(qf[t][s], kf, sv[ni]);
        }
      }
      if (it == jT) {
        const int rowg = jT*64 + wave*16 + quad*4;
        const int kv0 = it * 64;
        #pragma unroll
        for (int ni = 0; ni < 4; ++ni) {
          const int colg = kv0 + ni*16 + l16;
          #pragma unroll
          for (int r = 0; r < 4; ++r)
            if (colg > rowg + r) sv[ni][r] = -__builtin_inff();
        }
      }
      float rsum[4] = {0.f, 0.f, 0.f, 0.f};
      unsigned short pb[4][4];
      #pragma unroll
      for (int ni = 0; ni < 4; ++ni)
        #pragma unroll
        for (int r = 0; r < 4; ++r) {
          float p = __expf(sv[ni][r]);
          rsum[r] += p;
          pb[ni][r] = f2b(p);
        }
      #pragma unroll
      for (int r = 0; r < 4; ++r) {
        float s2 = rsum[r];
        s2 += __shfl_xor(s2, 1);
        s2 += __shfl_xor(s2, 2);
        s2 += __shfl_xor(s2, 4);
        s2 += __shfl_xor(s2, 8);
        lrow[t][r] += s2;
      }
      #pragma unroll
      for (int ni = 0; ni < 4; ++ni)
        #pragma unroll
        for (int r = 0; r < 4; ++r)
          Ps[t][wave*1152 + (quad*4 + r)*72 + ni*16 + l16] = pb[ni][r];
      __asm__ volatile("s_waitcnt lgkmcnt(0)" ::: "memory");
      #pragma unroll
      for (int s = 0; s < 2; ++s) {
        bf16x8 pf = __builtin_bit_cast(bf16x8,
          *(const s16x8*)&Ps[t][wave*1152 + l16*72 + s*32 + quad*8]);
        #pragma unroll
        for (int ni = 0; ni < 4; ++ni) {
          bf16x8 vf = __builtin_bit_cast(bf16x8,
            *(const s16x8*)&Vs[buf][(ni*16 + l16)*64 + (((s*4 + quad) ^ (l16 & 7)) * 8)]);
          accO[t][ni] = mfma16(pf, vf, accO[t][ni]);
        }
      }
    }
    __syncthreads();
  }

  #pragma unroll
  for (int t = 0; t < 2; ++t) {
    const int rowg = (t ? jB : jA)*64 + wave*16 + quad*4;
    #pragma unroll
    for (int ni = 0; ni < 4; ++ni)
      #pragma unroll
      for (int r = 0; r < 4; ++r) {
        float o = accO[t][ni][r] / lrow[t][r];
        outc[(size_t)(b*2048 + rowg + r) * 1024 + h*64 + ni*16 + l16] = f2b(o);
      }
  }
}

extern "C" void kernel_launch(void* const* d_in, const int* in_sizes, int n_in,
                              void* d_out, int out_size, void* d_ws, size_t ws_size,
                              hipStream_t stream) {
  (void)in_sizes; (void)n_in; (void)out_size; (void)ws_size;
  const float* x   = (const float*)d_in[0];
  const float* wq  = (const float*)d_in[1];
  const float* wk  = (const float*)d_in[2];
  const float* wv  = (const float*)d_in[3];
  const float* wo  = (const float*)d_in[4];
  const float* bo  = (const float*)d_in[5];
  const float* g1  = (const float*)d_in[6];
  const float* b1  = (const float*)d_in[7];
  const float* g2  = (const float*)d_in[8];
  const float* b2  = (const float*)d_in[9];
  const float* w1  = (const float*)d_in[10];
  const float* bf1 = (const float*)d_in[11];
  const float* w2  = (const float*)d_in[12];
  const float* bf2 = (const float*)d_in[13];
  float* out = (float*)d_out;

  unsigned short* ws    = (unsigned short*)d_ws;
  unsigned short* wqkvt = ws;                        // bf16 [3072][1024]
  unsigned short* wot   = wqkvt + 3*1024*1024;       // bf16 [1024][1024]
  unsigned short* w1t   = wot   + 1024*1024;         // bf16 [4096][1024]
  unsigned short* w2t   = w1t   + 4096*1024;         // bf16 [1024][4096]
  unsigned short* hbuf  = w2t   + 4096*1024;         // bf16 [4096][1024] (LN1/LN2 out)
  unsigned short* qkvb  = hbuf  + 4096*1024;         // bf16 [4096][3072]
  unsigned short* attnb = qkvb  + (size_t)4096*3072; // bf16 [4096][1024]
  float*          x2b   = (float*)(attnb + 4096*1024); // f32 [4096][1024]
  unsigned short* vTb   = (unsigned short*)x2b;      // bf16 [32][64][2048] — dead before x2b written
  unsigned short* midb  = qkvb;                      // bf16 [4096][4096] overlaps qkvb+attnb (dead)

  dim3 tb(32, 8);
  transpose_k<<<dim3(2,32,16), tb, 0, stream>>>(wq, wqkvt,             1024, 64, 65536, 65536);
  transpose_k<<<dim3(2,32,16), tb, 0, stream>>>(wk, wqkvt + 1024*1024, 1024, 64, 65536, 65536);
  transpose_k<<<dim3(2,32,16), tb, 0, stream>>>(wv, wqkvt + 2048*1024, 1024, 64, 65536, 65536);
  transpose_k<<<dim3(32,32,1),  tb, 0, stream>>>(wo, wot, 1024, 1024, 0, 0);
  transpose_k<<<dim3(128,32,1), tb, 0, stream>>>(w1, w1t, 1024, 4096, 0, 0);
  transpose_k<<<dim3(32,128,1), tb, 0, stream>>>(w2, w2t, 4096, 1024, 0, 0);

  ln_kernel<<<4096, 256, 0, stream>>>(x, g1, b1, hbuf);
  gemm_bt<false,false,false,false><<<dim3(24,32), 256, 0, stream>>>(hbuf, wqkvt, nullptr, nullptr, qkvb, 4096, 3072, 1024);
  vtrans_k<<<dim3(64,2,32), tb, 0, stream>>>(qkvb, vTb);
  attn_kernel<<<dim3(16,32), 256, 0, stream>>>(qkvb, vTb, attnb);
  gemm_n1024<<<512, 256, 0, stream>>>(attnb, wot, bo, x, x2b, 4096, 1024, 1024);
  ln_kernel<<<4096, 256, 0, stream>>>(x2b, g2, b2, hbuf);
  gemm_bt<true,true,false,false><<<dim3(32,32), 256, 0, stream>>>(hbuf, w1t, bf1, nullptr, midb, 4096, 4096, 1024);
  gemm_n1024<<<512, 256, 0, stream>>>(midb, w2t, bf2, x2b, out, 4096, 1024, 4096);
}

// Round 11
// 343.660 us; speedup vs baseline: 1.1481x; 1.0666x over previous
//
#include <hip/hip_runtime.h>
#include <hip/hip_bf16.h>

typedef __bf16 bf16x8 __attribute__((ext_vector_type(8)));
typedef float f32x4 __attribute__((ext_vector_type(4)));
typedef short s16x8 __attribute__((ext_vector_type(8)));

#define DEV __device__ __forceinline__

DEV float b2f(unsigned short u) {
  unsigned int x = ((unsigned int)u) << 16;
  return __builtin_bit_cast(float, x);
}
DEV unsigned short f2b(float f) {
  unsigned int x = __builtin_bit_cast(unsigned int, f);
  x += 0x7fffu + ((x >> 16) & 1u);
  return (unsigned short)(x >> 16);
}
DEV unsigned int f2b2(float a, float b) {
  float2 t; t.x = a; t.y = b;
  __hip_bfloat162 v = __float22bfloat162_rn(t);
  unsigned int r;
  __builtin_memcpy(&r, &v, 4);
  return r;
}
DEV f32x4 mfma16(bf16x8 a, bf16x8 b, f32x4 c) {
  return __builtin_amdgcn_mfma_f32_16x16x32_bf16(a, b, c, 0, 0, 0);
}
DEV void gl2lds16(const unsigned short* g, unsigned short* l) {
  __builtin_amdgcn_global_load_lds(
      (const __attribute__((address_space(1))) void*)g,
      (__attribute__((address_space(3))) void*)l, 16, 0, 0);
}

// ------- tiled transpose + f32->bf16 convert: in[K][N] f32 (+z) -> out[N][K] bf16 -------
__global__ __launch_bounds__(256)
void transpose_k(const float* __restrict__ in, unsigned short* __restrict__ out,
                 int K, int N, long zin, long zout) {
  __shared__ float tile[32][33];
  in  += (size_t)blockIdx.z * zin;
  out += (size_t)blockIdx.z * zout;
  int n0 = blockIdx.x * 32, k0 = blockIdx.y * 32;
  int tx = threadIdx.x, ty = threadIdx.y;
  #pragma unroll
  for (int i = ty; i < 32; i += 8)
    tile[i][tx] = in[(size_t)(k0 + i) * N + n0 + tx];
  __syncthreads();
  #pragma unroll
  for (int i = ty; i < 32; i += 8)
    out[(size_t)(n0 + i) * K + k0 + tx] = f2b(tile[tx][i]);
}

// ------- fused QKV weight transpose: wq/wk/wv [16][1024][64] f32 -> [3072][1024] bf16 ----
__global__ __launch_bounds__(256)
void transpose_qkv(const float* __restrict__ wq, const float* __restrict__ wk,
                   const float* __restrict__ wv, unsigned short* __restrict__ out) {
  __shared__ float tile[32][33];
  const int z = blockIdx.z;   // 0..47
  const float* in = (z < 16) ? (wq + (size_t)z * 65536)
                  : (z < 32) ? (wk + (size_t)(z - 16) * 65536)
                             : (wv + (size_t)(z - 32) * 65536);
  unsigned short* o = out + (size_t)z * 65536;
  int n0 = blockIdx.x * 32, k0 = blockIdx.y * 32;   // N=64, K=1024
  int tx = threadIdx.x, ty = threadIdx.y;
  #pragma unroll
  for (int i = ty; i < 32; i += 8)
    tile[i][tx] = in[(size_t)(k0 + i) * 64 + n0 + tx];
  __syncthreads();
  #pragma unroll
  for (int i = ty; i < 32; i += 8)
    o[(size_t)(n0 + i) * 1024 + k0 + tx] = f2b(tile[tx][i]);
}

// ---------------- LayerNorm over rows of 1024: f32 in -> bf16 out ----------------
__global__ __launch_bounds__(256)
void ln_kernel(const float* __restrict__ x, const float* __restrict__ g,
               const float* __restrict__ b, unsigned short* __restrict__ o) {
  __shared__ float rs[4];
  __shared__ float rq[4];
  int row = blockIdx.x, tid = threadIdx.x;
  const float* xr = x + (size_t)row * 1024;
  float4 raw = ((const float4*)xr)[tid];
  float s = raw.x + raw.y + raw.z + raw.w;
  float q = raw.x*raw.x + raw.y*raw.y + raw.z*raw.z + raw.w*raw.w;
  #pragma unroll
  for (int off = 32; off > 0; off >>= 1) {
    s += __shfl_down(s, off);
    q += __shfl_down(q, off);
  }
  int wave = tid >> 6;
  if ((tid & 63) == 0) { rs[wave] = s; rq[wave] = q; }
  __syncthreads();
  float ts = rs[0] + rs[1] + rs[2] + rs[3];
  float tq = rq[0] + rq[1] + rq[2] + rq[3];
  float mean = ts * (1.0f/1024.0f);
  float var = tq * (1.0f/1024.0f) - mean*mean;
  float rstd = rsqrtf(var + 1e-5f);
  float4 gr = ((const float4*)g)[tid];
  float4 br = ((const float4*)b)[tid];
  float o0 = (raw.x-mean)*rstd*gr.x + br.x;
  float o1 = (raw.y-mean)*rstd*gr.y + br.y;
  float o2 = (raw.z-mean)*rstd*gr.z + br.z;
  float o3 = (raw.w-mean)*rstd*gr.w + br.w;
  uint2 ov;
  ov.x = f2b2(o0, o1);
  ov.y = f2b2(o2, o3);
  ((uint2*)(o + (size_t)row * 1024))[tid] = ov;
}

// ------- GEMM 128x128: C[M][N] = A * Bt^T (+f32 bias/resid, relu), dbuf LDS -------
// VFUSE: n-blocks with n0>=2048 (V region of QKV) write transposed into vT instead.
template<bool RELU, bool BIAS, bool RESID, bool OUTF32, bool VFUSE>
__global__ __launch_bounds__(256)
void gemm_bt(const unsigned short* __restrict__ A, const unsigned short* __restrict__ Bt,
             const float* __restrict__ bias, const float* __restrict__ resid,
             void* __restrict__ Cv, unsigned short* __restrict__ vT, int M, int N, int K) {
  __shared__ unsigned short As[2][128*32];
  __shared__ unsigned short Bs[2][128*32];
  const int tid = threadIdx.x;
  const int lane = tid & 63;
  const int quad = lane >> 4, l16 = lane & 15;
  const int wave = tid >> 6;
  const int m0 = blockIdx.y * 128, n0 = blockIdx.x * 128;
  const int wm = (wave >> 1) * 64, wn = (wave & 1) * 64;

  f32x4 acc[4][4];
  #pragma unroll
  for (int i = 0; i < 4; ++i)
    #pragma unroll
    for (int j = 0; j < 4; ++j) acc[i][j] = (f32x4){0.f, 0.f, 0.f, 0.f};

  const int srow = tid >> 2;
  const int scol = (tid & 3) * 8;
  const unsigned short* Ab = A + (size_t)m0 * K;
  const unsigned short* Bb = Bt + (size_t)n0 * K;

  auto stage = [&](int buf, int k0) {
    gl2lds16(Ab + (size_t)srow * K + k0 + scol,        &As[buf][tid * 8]);
    gl2lds16(Ab + (size_t)(srow + 64) * K + k0 + scol, &As[buf][2048 + tid * 8]);
    gl2lds16(Bb + (size_t)srow * K + k0 + scol,        &Bs[buf][tid * 8]);
    gl2lds16(Bb + (size_t)(srow + 64) * K + k0 + scol, &Bs[buf][2048 + tid * 8]);
  };

  const int niter = K >> 5;
  stage(0, 0);
  __syncthreads();

  for (int it = 0; it < niter; ++it) {
    const int buf = it & 1;
    if (it + 1 < niter) stage(buf ^ 1, (it + 1) * 32);
    bf16x8 af[4], bfr[4];
    #pragma unroll
    for (int i = 0; i < 4; ++i)
      af[i] = __builtin_bit_cast(bf16x8, *(const s16x8*)&As[buf][(wm + i*16 + l16)*32 + quad*8]);
    #pragma unroll
    for (int j = 0; j < 4; ++j)
      bfr[j] = __builtin_bit_cast(bf16x8, *(const s16x8*)&Bs[buf][(wn + j*16 + l16)*32 + quad*8]);
    #pragma unroll
    for (int i = 0; i < 4; ++i)
      #pragma unroll
      for (int j = 0; j < 4; ++j)
        acc[i][j] = mfma16(af[i], bfr[j], acc[i][j]);
    __syncthreads();
  }

  if (VFUSE && n0 >= 2048) {
    // V region: write transposed into vT[bh][d][2048]
    #pragma unroll
    for (int i = 0; i < 4; ++i) {
      const int row = m0 + wm + i*16 + quad*4;       // global token
      const int b = row >> 11, tloc = row & 2047;
      #pragma unroll
      for (int j = 0; j < 4; ++j) {
        const int col = n0 + wn + j*16 + l16;
        const int h = (col - 2048) >> 6, d = col & 63;
        ushort4 pk;
        pk.x = f2b(acc[i][j][0]);
        pk.y = f2b(acc[i][j][1]);
        pk.z = f2b(acc[i][j][2]);
        pk.w = f2b(acc[i][j][3]);
        *(ushort4*)&vT[((size_t)((b*16 + h)*64 + d))*2048 + tloc] = pk;
      }
    }
    return;
  }

  #pragma unroll
  for (int i = 0; i < 4; ++i) {
    const int row = m0 + wm + i*16 + quad*4;
    #pragma unroll
    for (int j = 0; j < 4; ++j) {
      const int col = n0 + wn + j*16 + l16;
      float bv = 0.f;
      if (BIAS) bv = bias[col];
      #pragma unroll
      for (int r = 0; r < 4; ++r) {
        float v = acc[i][j][r] + bv;
        if (RESID) v += resid[(size_t)(row + r) * N + col];
        if (RELU) v = fmaxf(v, 0.f);
        if (OUTF32) ((float*)Cv)[(size_t)(row + r) * N + col] = v;
        else ((unsigned short*)Cv)[(size_t)(row + r) * N + col] = f2b(v);
      }
    }
  }
}

// ------- GEMM 64x128, BK=64, chunk-XOR swizzled LDS, dbuf — for N=1024 outputs -------
__global__ __launch_bounds__(256)
void gemm_n1024(const unsigned short* __restrict__ A, const unsigned short* __restrict__ Bt,
                const float* __restrict__ bias, const float* __restrict__ resid,
                float* __restrict__ C, int M, int N, int K) {
  __shared__ unsigned short As[2][64*64];
  __shared__ unsigned short Bs[2][128*64];
  const int tid = threadIdx.x;
  const int lane = tid & 63;
  const int quad = lane >> 4, l16 = lane & 15;
  const int wave = tid >> 6;
  const int id = blockIdx.x;
  const int xcd = id & 7, i2 = id >> 3;
  const int mt = (xcd << 3) | (i2 >> 3);
  const int nt = i2 & 7;
  const int m0 = mt * 64, n0 = nt * 128;
  const int wm = (wave >> 1) * 32, wn = (wave & 1) * 64;

  f32x4 acc[2][4];
  #pragma unroll
  for (int i = 0; i < 2; ++i)
    #pragma unroll
    for (int j = 0; j < 4; ++j) acc[i][j] = (f32x4){0.f, 0.f, 0.f, 0.f};

  const int srow = tid >> 3;
  const int scc  = ((tid & 7) ^ (srow & 7)) * 8;
  const unsigned short* Ab = A + (size_t)m0 * K;
  const unsigned short* Bb = Bt + (size_t)n0 * K;

  auto stage = [&](int buf, int k0) {
    gl2lds16(Ab + (size_t)srow * K + k0 + scc,         &As[buf][tid * 8]);
    gl2lds16(Ab + (size_t)(srow + 32) * K + k0 + scc,  &As[buf][2048 + tid * 8]);
    gl2lds16(Bb + (size_t)srow * K + k0 + scc,         &Bs[buf][tid * 8]);
    gl2lds16(Bb + (size_t)(srow + 32) * K + k0 + scc,  &Bs[buf][2048 + tid * 8]);
    gl2lds16(Bb + (size_t)(srow + 64) * K + k0 + scc,  &Bs[buf][4096 + tid * 8]);
    gl2lds16(Bb + (size_t)(srow + 96) * K + k0 + scc,  &Bs[buf][6144 + tid * 8]);
  };

  const int niter = K >> 6;
  stage(0, 0);
  __syncthreads();

  for (int it = 0; it < niter; ++it) {
    const int buf = it & 1;
    if (it + 1 < niter) stage(buf ^ 1, (it + 1) * 64);
    #pragma unroll
    for (int s = 0; s < 2; ++s) {
      bf16x8 af[2], bfr[4];
      #pragma unroll
      for (int i = 0; i < 2; ++i) {
        const int R = wm + i*16 + l16;
        af[i] = __builtin_bit_cast(bf16x8,
          *(const s16x8*)&As[buf][R*64 + (((s*4 + quad) ^ (R & 7)) * 8)]);
      }
      #pragma unroll
      for (int j = 0; j < 4; ++j) {
        const int R = wn + j*16 + l16;
        bfr[j] = __builtin_bit_cast(bf16x8,
          *(const s16x8*)&Bs[buf][R*64 + (((s*4 + quad) ^ (R & 7)) * 8)]);
      }
      #pragma unroll
      for (int i = 0; i < 2; ++i)
        #pragma unroll
        for (int j = 0; j < 4; ++j)
          acc[i][j] = mfma16(af[i], bfr[j], acc[i][j]);
    }
    __syncthreads();
  }

  #pragma unroll
  for (int i = 0; i < 2; ++i) {
    const int row = m0 + wm + i*16 + quad*4;
    #pragma unroll
    for (int j = 0; j < 4; ++j) {
      const int col = n0 + wn + j*16 + l16;
      const float bv = bias[col];
      #pragma unroll
      for (int r = 0; r < 4; ++r)
        C[(size_t)(row + r) * N + col] = acc[i][j][r] + bv + resid[(size_t)(row + r) * N + col];
    }
  }
}

// ---------------- causal flash attention, paired q-tiles + gl2lds double-buffer ------
// Row sums via ones-vector MFMA (accS); packed bf16 cvt; single Ps buffer.
__global__ __launch_bounds__(256)
void attn_kernel(const unsigned short* __restrict__ qkv,
                 const unsigned short* __restrict__ vT,
                 unsigned short* __restrict__ outc) {
  __shared__ unsigned short Ks[2][64*64];   // [kv][d], chunk-XOR swizzled
  __shared__ unsigned short Vs[2][64*64];   // [d][kv], chunk-XOR swizzled
  __shared__ unsigned short Ps[4*16*72];    // per-wave P [16][72]
  const int tid = threadIdx.x, lane = tid & 63, wave = tid >> 6;
  const int quad = lane >> 4, l16 = lane & 15;
  const int bh = blockIdx.y, b = bh >> 4, h = bh & 15;
  const int jA = blockIdx.x, jB = 31 - jA;
  const size_t tokbase = (size_t)b * 2048 * 3072;
  const unsigned short* Q  = qkv + tokbase + h * 64;
  const unsigned short* Kg = qkv + tokbase + 1024 + h * 64;
  const unsigned short* Vg = vT + (size_t)bh * 64 * 2048;

  const s16x8 ones_s = {0x3F80, 0x3F80, 0x3F80, 0x3F80, 0x3F80, 0x3F80, 0x3F80, 0x3F80};
  const bf16x8 onesf = __builtin_bit_cast(bf16x8, ones_s);

  bf16x8 qf[2][2];
  #pragma unroll
  for (int t = 0; t < 2; ++t) {
    const int qrow = (t ? jB : jA) * 64 + wave * 16 + l16;
    #pragma unroll
    for (int s = 0; s < 2; ++s) {
      s16x8 raw = *(const s16x8*)(Q + (size_t)qrow * 3072 + s * 32 + quad * 8);
      unsigned short* rp = (unsigned short*)&raw;
      #pragma unroll
      for (int j = 0; j < 8; ++j) rp[j] = f2b(b2f(rp[j]) * 0.03125f);
      qf[t][s] = __builtin_bit_cast(bf16x8, raw);
    }
  }

  f32x4 accO[2][4];
  f32x4 accS[2] = {(f32x4){0.f,0.f,0.f,0.f}, (f32x4){0.f,0.f,0.f,0.f}};
  #pragma unroll
  for (int t = 0; t < 2; ++t)
    #pragma unroll
    for (int i = 0; i < 4; ++i) accO[t][i] = (f32x4){0.f, 0.f, 0.f, 0.f};

  const int r8 = lane >> 3;
  const int cs = (((lane & 7) ^ r8) * 8);

  auto stage = [&](int buf, int kv0) {
    #pragma unroll
    for (int i = 0; i < 2; ++i) {
      int row = wave * 16 + i * 8;
      gl2lds16(Kg + (size_t)(kv0 + row + r8) * 3072 + cs, &Ks[buf][row * 64 + lane * 8]);
      gl2lds16(Vg + (size_t)(row + r8) * 2048 + kv0 + cs, &Vs[buf][row * 64 + lane * 8]);
    }
  };

  const int ntile = jB + 1;
  stage(0, 0);
  __syncthreads();

  for (int it = 0; it < ntile; ++it) {
    const int buf = it & 1;
    if (it + 1 < ntile) stage(buf ^ 1, (it + 1) * 64);

    #pragma unroll
    for (int t = 0; t < 2; ++t) {
      const int jT = t ? jB : jA;
      if (it > jT) continue;
      f32x4 sv[4];
      #pragma unroll
      for (int ni = 0; ni < 4; ++ni) {
        sv[ni] = (f32x4){0.f, 0.f, 0.f, 0.f};
        #pragma unroll
        for (int s = 0; s < 2; ++s) {
          bf16x8 kf = __builtin_bit_cast(bf16x8,
            *(const s16x8*)&Ks[buf][(ni*16 + l16)*64 + (((s*4 + quad) ^ (l16 & 7)) * 8)]);
          sv[ni] = mfma16(qf[t][s], kf, sv[ni]);
        }
      }
      if (it == jT) {
        const int rowg = jT*64 + wave*16 + quad*4;
        const int kv0 = it * 64;
        #pragma unroll
        for (int ni = 0; ni < 4; ++ni) {
          const int colg = kv0 + ni*16 + l16;
          #pragma unroll
          for (int r = 0; r < 4; ++r)
            if (colg > rowg + r) sv[ni][r] = -__builtin_inff();
        }
      }
      // p = exp(s), fixed max=0; packed bf16 cvt; store to per-wave Ps
      #pragma unroll
      for (int ni = 0; ni < 4; ++ni) {
        float p0 = __expf(sv[ni][0]);
        float p1 = __expf(sv[ni][1]);
        float p2 = __expf(sv[ni][2]);
        float p3 = __expf(sv[ni][3]);
        unsigned int u01 = f2b2(p0, p1);
        unsigned int u23 = f2b2(p2, p3);
        const int base = wave*1152 + ni*16 + l16;
        Ps[base + (quad*4 + 0)*72] = (unsigned short)u01;
        Ps[base + (quad*4 + 1)*72] = (unsigned short)(u01 >> 16);
        Ps[base + (quad*4 + 2)*72] = (unsigned short)u23;
        Ps[base + (quad*4 + 3)*72] = (unsigned short)(u23 >> 16);
      }
      __asm__ volatile("s_waitcnt lgkmcnt(0)" ::: "memory");
      #pragma unroll
      for (int s = 0; s < 2; ++s) {
        bf16x8 pf = __builtin_bit_cast(bf16x8,
          *(const s16x8*)&Ps[wave*1152 + l16*72 + s*32 + quad*8]);
        accS[t] = mfma16(pf, onesf, accS[t]);   // row sums via ones-column MFMA
        #pragma unroll
        for (int ni = 0; ni < 4; ++ni) {
          bf16x8 vf = __builtin_bit_cast(bf16x8,
            *(const s16x8*)&Vs[buf][(ni*16 + l16)*64 + (((s*4 + quad) ^ (l16 & 7)) * 8)]);
          accO[t][ni] = mfma16(pf, vf, accO[t][ni]);
        }
      }
    }
    __syncthreads();
  }

  #pragma unroll
  for (int t = 0; t < 2; ++t) {
    const int rowg = (t ? jB : jA)*64 + wave*16 + quad*4;
    float inv[4];
    #pragma unroll
    for (int r = 0; r < 4; ++r) inv[r] = __builtin_amdgcn_rcpf(accS[t][r]);
    #pragma unroll
    for (int ni = 0; ni < 4; ++ni)
      #pragma unroll
      for (int r = 0; r < 4; ++r)
        outc[(size_t)(b*2048 + rowg + r) * 1024 + h*64 + ni*16 + l16]
          = f2b(accO[t][ni][r] * inv[r]);
  }
}

extern "C" void kernel_launch(void* const* d_in, const int* in_sizes, int n_in,
                              void* d_out, int out_size, void* d_ws, size_t ws_size,
                              hipStream_t stream) {
  (void)in_sizes; (void)n_in; (void)out_size; (void)ws_size;
  const float* x   = (const float*)d_in[0];
  const float* wq  = (const float*)d_in[1];
  const float* wk  = (const float*)d_in[2];
  const float* wv  = (const float*)d_in[3];
  const float* wo  = (const float*)d_in[4];
  const float* bo  = (const float*)d_in[5];
  const float* g1  = (const float*)d_in[6];
  const float* b1  = (const float*)d_in[7];
  const float* g2  = (const float*)d_in[8];
  const float* b2  = (const float*)d_in[9];
  const float* w1  = (const float*)d_in[10];
  const float* bf1 = (const float*)d_in[11];
  const float* w2  = (const float*)d_in[12];
  const float* bf2 = (const float*)d_in[13];
  float* out = (float*)d_out;

  unsigned short* ws    = (unsigned short*)d_ws;
  unsigned short* wqkvt = ws;                        // bf16 [3072][1024]
  unsigned short* wot   = wqkvt + 3*1024*1024;       // bf16 [1024][1024]
  unsigned short* w1t   = wot   + 1024*1024;         // bf16 [4096][1024]
  unsigned short* w2t   = w1t   + 4096*1024;         // bf16 [1024][4096]
  unsigned short* hbuf  = w2t   + 4096*1024;         // bf16 [4096][1024] (LN1/LN2 out)
  unsigned short* qkvb  = hbuf  + 4096*1024;         // bf16 [4096][3072] (V region unused)
  unsigned short* attnb = qkvb  + (size_t)4096*3072; // bf16 [4096][1024]
  float*          x2b   = (float*)(attnb + 4096*1024); // f32 [4096][1024]
  unsigned short* vTb   = (unsigned short*)x2b;      // bf16 [32][64][2048] — dead before x2b written
  unsigned short* midb  = qkvb;                      // bf16 [4096][4096] overlaps qkvb+attnb (dead)

  dim3 tb(32, 8);
  transpose_qkv<<<dim3(2,32,48), tb, 0, stream>>>(wq, wk, wv, wqkvt);
  transpose_k<<<dim3(32,32,1),  tb, 0, stream>>>(wo, wot, 1024, 1024, 0, 0);
  transpose_k<<<dim3(128,32,1), tb, 0, stream>>>(w1, w1t, 1024, 4096, 0, 0);
  transpose_k<<<dim3(32,128,1), tb, 0, stream>>>(w2, w2t, 4096, 1024, 0, 0);

  ln_kernel<<<4096, 256, 0, stream>>>(x, g1, b1, hbuf);
  // QKV GEMM with fused V-transpose epilogue (V region -> vTb)
  gemm_bt<false,false,false,false,true><<<dim3(24,32), 256, 0, stream>>>(
      hbuf, wqkvt, nullptr, nullptr, qkvb, vTb, 4096, 3072, 1024);
  attn_kernel<<<dim3(16,32), 256, 0, stream>>>(qkvb, vTb, attnb);
  gemm_n1024<<<512, 256, 0, stream>>>(attnb, wot, bo, x, x2b, 4096, 1024, 1024);
  ln_kernel<<<4096, 256, 0, stream>>>(x2b, g2, b2, hbuf);
  gemm_bt<true,true,false,false,false><<<dim3(32,32), 256, 0, stream>>>(
      hbuf, w1t, bf1, nullptr, midb, nullptr, 4096, 4096, 1024);
  gemm_n1024<<<512, 256, 0, stream>>>(midb, w2t, bf2, x2b, out, 4096, 1024, 4096);
}